// Round 7
// baseline (72.393 us; speedup 1.0000x reference)
//
#include <hip/hip_runtime.h>
#include <hip/hip_bf16.h>
#include <math.h>

// Problem constants
constexpr int kB = 256, kC = 512, kT = 56, kP = 512;
constexpr int kCT = kC * kT;  // 28672 floats per row

typedef short v4s __attribute__((ext_vector_type(4)));
typedef short v8s __attribute__((ext_vector_type(8)));
typedef float v4f __attribute__((ext_vector_type(4)));
typedef float v16f __attribute__((ext_vector_type(16)));

__device__ __forceinline__ unsigned pack_bf16(float a, float b) {
  __hip_bfloat16 ha = __float2bfloat16(a);
  __hip_bfloat16 hb = __float2bfloat16(b);
  unsigned short ua, ub;
  __builtin_memcpy(&ua, &ha, 2);
  __builtin_memcpy(&ub, &hb, 2);
  return (unsigned)ua | ((unsigned)ub << 16);
}

__device__ __forceinline__ v4s frag2(unsigned w0, unsigned w1) {
  unsigned u[2] = {w0, w1};
  v4s s;
  __builtin_memcpy(&s, u, 8);
  return s;
}

__device__ __forceinline__ v8s frag8(uint4 u) {
  v8s s;
  __builtin_memcpy(&s, &u, 16);
  return s;
}

__device__ __forceinline__ float bfl(unsigned u) {
  unsigned v = u << 16;
  float f;
  __builtin_memcpy(&f, &v, 4);
  return f;
}
__device__ __forceinline__ float bfh(unsigned u) {
  unsigned v = u & 0xffff0000u;
  float f;
  __builtin_memcpy(&f, &v, 4);
  return f;
}
__device__ __forceinline__ unsigned cvtpk(float lo, float hi) {
  unsigned r;
  asm("v_cvt_pk_bf16_f32 %0, %1, %2" : "=v"(r) : "v"(lo), "v"(hi));
  return r;
}

// ===========================================================================
// PREP (unchanged from r6): 4 chunks of 128 c; coalesced fp32 read, LDS
// transpose, pack bf16 t-major xt/pt, fused norms.
// ===========================================================================
__global__ __launch_bounds__(512) void prep_kernel(
    const float* __restrict__ x, const float* __restrict__ proto,
    unsigned* __restrict__ xt, unsigned* __restrict__ pt,
    float* __restrict__ xn, float* __restrict__ pn) {
  __shared__ float tile[128 * 57];  // 29,184 B
  __shared__ float part[8][64];

  const int tid = threadIdx.x;
  const int n = blockIdx.x;
  const bool isx = (n < kB);
  const int row = isx ? n : (n - kB);
  const float* src = (isx ? x : proto) + (size_t)row * kCT;

  const int g = tid >> 6, tt = tid & 63;
  float nacc = 0.f;

#pragma unroll 1
  for (int ch = 0; ch < 4; ++ch) {
    const float* csrc = src + ch * (128 * 56);
#pragma unroll
    for (int it = 0; it < 4; ++it) {
      const int idx = it * 512 + tid;
      if (idx < 1792) {
        const int f0 = idx * 4;
        float4 v = *(const float4*)(csrc + f0);
        int c = (int)(((unsigned)f0 * 74899u) >> 22);  // f0 / 56
        int t = f0 - c * 56;  // 56%4==0 -> no row crossing
        tile[c * 57 + t] = v.x;
        tile[c * 57 + t + 1] = v.y;
        tile[c * 57 + t + 2] = v.z;
        tile[c * 57 + t + 3] = v.w;
      }
    }
    __syncthreads();
    if (tt < 56) {
#pragma unroll
      for (int cc2 = 0; cc2 < 16; ++cc2) {
        float u = tile[(g * 16 + cc2) * 57 + tt];
        nacc = fmaf(u, u, nacc);
      }
    }
#pragma unroll
    for (int it = 0; it < 7; ++it) {
      const int id = it * 512 + tid;
      const int t = id >> 6;
      const int cw = id & 63;
      float g0 = tile[(2 * cw) * 57 + t];
      float g1 = tile[(2 * cw + 1) * 57 + t];
      unsigned wd = pack_bf16(g0, g1);
      if (isx)
        xt[((size_t)(t * kB + row)) * 256 + ch * 64 + cw] = wd;
      else
        pt[((size_t)(t * kP + row)) * 256 + ch * 64 + cw] = wd;
    }
    __syncthreads();
  }

  part[g][tt] = nacc;
  __syncthreads();
  if (tid < 56) {
    float s = 0.f;
#pragma unroll
    for (int gg = 0; gg < 8; ++gg) s += part[gg][tid];
    float r = sqrtf(s);
    if (isx) xn[row * 56 + tid] = r; else pn[row * 56 + tid] = r;
  }
}

// ===========================================================================
// MAIN v4: as r6 (32x32x16 MFMA, 64b x 64p block, 4 waves, XOR-swizzled LDS,
// in-register xw, no-max softmax) plus:
//  - template<TPB>: TPB t per block -> grid z = 56/TPB. TPB=2 gives 896
//    blocks (3.5/CU) for real TLP; TPB=4 is the r6 geometry fallback.
//  - bijective XCD swizzle (nwg % 8 == 0): each XCD takes contiguous
//    (bx,by) planes -> xt/pt slices go L2-resident.
//  - xn/pn preloaded into LDS at prologue: epilogue norm reads are LDS
//    broadcasts, not stride-56 global scalars.
// ===========================================================================
constexpr int CW = 32;           // chunk words (=64 c)
constexpr int TILE = 64 * CW;    // 2048 words
constexpr int BUFW = 3 * TILE;   // x + xw + p = 6144 words

template <int TPB>
__global__ __launch_bounds__(256, 3) void proto_gemm_kernel(
    const unsigned* __restrict__ xt, const unsigned* __restrict__ pt,
    const float* __restrict__ fcw,
    const float* __restrict__ xn, const float* __restrict__ pn,
    float* __restrict__ part) {
  __shared__ __align__(16) unsigned lds[2 * BUFW];  // 49,152 B
  __shared__ float xnL[TPB * 64], pnL[TPB * 64];

  const int tid = threadIdx.x;
  const int l = tid & 63;
  const int w = tid >> 6;     // wave 0..3
  const int wm = w >> 1;      // b half
  const int wn = w & 1;       // p half

  // bijective XCD swizzle (nwg = 32 * 56/TPB, multiple of 8)
  const int nwg = 32 * (56 / TPB);
  int bid = (int)blockIdx.x + 4 * ((int)blockIdx.y + 8 * (int)blockIdx.z);
  bid = (bid & 7) * (nwg >> 3) + (bid >> 3);
  const int b0 = (bid & 3) * 64;
  const int p0 = ((bid >> 2) & 7) * 64;
  const int tg = bid >> 5;    // t = tg*TPB .. tg*TPB+TPB-1

  // preload norms for this block's t-range into LDS
  if (tid < TPB * 64) {
    const int tl = tid >> 6, r = tid & 63;
    xnL[tl * 64 + r] = xn[(b0 + r) * 56 + tg * TPB + tl];
    pnL[tl * 64 + r] = pn[(p0 + r) * 56 + tg * TPB + tl];
  }

  // staging: ids {tid, tid+256}: row = id>>3 (8 thr/row), colw = (tid&7)*4
  const int srow = tid >> 3;           // 0..31
  const int scolw = (tid & 7) * 4;
  const int ssw = (srow & 7) * 4;      // same for srow and srow+32
  const int lwA = srow * CW + (scolw ^ ssw);
  const int lwB = (srow + 32) * CW + (scolw ^ ssw);

  // fragment geometry (32x32x16: lane -> row l&31, k-half l>>5)
  const int fr = l & 31;
  const int hi = l >> 5;
  const int sw4 = (l & 7) * 4;
  const int axb = (wm * 32 + fr) * CW;  // x/xw row base (words)
  const int pxb = (wn * 32 + fr) * CW;  // p row base

  v16f aD, aW, sac, nac;
#pragma unroll
  for (int i = 0; i < 16; ++i) { aD[i] = 0.f; aW[i] = 0.f; sac[i] = 0.f; nac[i] = 0.f; }

  uint4 Ax0, Ax1, Ap0, Ap1;
  float4 Af0, Af1;
  uint4 Bx0, Bx1, Bp0, Bp1;
  float4 Bf0, Bf1;

#define LOAD_REGS(S, CC) do { \
    const int t_ = tg * TPB + ((CC) >> 3); \
    const int ch_ = (CC) & 7; \
    const unsigned* gx_ = xt + ((size_t)(t_ * kB + b0 + srow)) * 256 + ch_ * CW + scolw; \
    const unsigned* gp_ = pt + ((size_t)(t_ * kP + p0 + srow)) * 256 + ch_ * CW + scolw; \
    S##x0 = *(const uint4*)(gx_); \
    S##x1 = *(const uint4*)(gx_ + 32 * 256); \
    S##p0 = *(const uint4*)(gp_); \
    S##p1 = *(const uint4*)(gp_ + 32 * 256); \
    const float* gf_ = fcw + ch_ * 64 + (tid & 7) * 8; \
    S##f0 = *(const float4*)(gf_); \
    S##f1 = *(const float4*)(gf_ + 4); \
  } while (0)

#define WMUL(xv, fa, fb, out) do { \
    out.x = cvtpk(bfl(xv.x) * fa.x, bfh(xv.x) * fa.y); \
    out.y = cvtpk(bfl(xv.y) * fa.z, bfh(xv.y) * fa.w); \
    out.z = cvtpk(bfl(xv.z) * fb.x, bfh(xv.z) * fb.y); \
    out.w = cvtpk(bfl(xv.w) * fb.z, bfh(xv.w) * fb.w); \
  } while (0)

#define STORE_LDS(S, CC) do { \
    unsigned* b_ = lds + ((CC) & 1) * BUFW; \
    *(uint4*)(b_ + lwA) = S##x0; \
    *(uint4*)(b_ + lwB) = S##x1; \
    uint4 w0_, w1_; \
    WMUL(S##x0, S##f0, S##f1, w0_); \
    WMUL(S##x1, S##f0, S##f1, w1_); \
    *(uint4*)(b_ + TILE + lwA) = w0_; \
    *(uint4*)(b_ + TILE + lwB) = w1_; \
    *(uint4*)(b_ + 2 * TILE + lwA) = S##p0; \
    *(uint4*)(b_ + 2 * TILE + lwB) = S##p1; \
  } while (0)

  auto compute = [&](int cc) {
    const unsigned* bx = lds + (cc & 1) * BUFW;
#pragma unroll
    for (int ks = 0; ks < 4; ++ks) {
      const int col = (ks * 8 + hi * 4) ^ sw4;
      uint4 xr = *(const uint4*)(bx + axb + col);
      uint4 wr = *(const uint4*)(bx + TILE + axb + col);
      uint4 pr = *(const uint4*)(bx + 2 * TILE + pxb + col);
      v8s xf = frag8(xr), wf = frag8(wr), pf = frag8(pr);
      aD = __builtin_amdgcn_mfma_f32_32x32x16_bf16(xf, pf, aD, 0, 0, 0);
      aW = __builtin_amdgcn_mfma_f32_32x32x16_bf16(wf, pf, aW, 0, 0, 0);
    }
    if ((cc & 7) == 7) {
      // end of one t: sim = D/(xn*pn); s += exp(sim); n += exp(sim)*W.
      // |sim| <= 1 (cosine) -> exp bounded, no running max needed.
      const int tl = cc >> 3;
      const float pnv = pnL[tl * 64 + wn * 32 + fr];
#pragma unroll
      for (int i = 0; i < 16; ++i) {
        const int drow = (i & 3) + 8 * (i >> 2) + 4 * hi;  // m74/m101 C/D map
        float xnv = xnL[tl * 64 + wm * 32 + drow];
        float den = fmaxf(xnv * pnv, 1e-8f);
        float sim = aD[i] * __builtin_amdgcn_rcpf(den);
        float e = __expf(sim);
        sac[i] += e;
        nac[i] = fmaf(e, aW[i], nac[i]);
        aD[i] = 0.f;
        aW[i] = 0.f;
      }
    }
  };

  // prologue
  LOAD_REGS(A, 0);
  STORE_LDS(A, 0);
  LOAD_REGS(B, 1);
  __syncthreads();

  constexpr int NCC = TPB * 8;
#pragma unroll 1
  for (int cc = 0; cc < NCC; cc += 2) {
    if (cc + 1 < NCC) STORE_LDS(B, cc + 1);
    if (cc + 2 < NCC) LOAD_REGS(A, cc + 2);
    compute(cc);
    __syncthreads();
    if (cc + 2 < NCC) STORE_LDS(A, cc + 2);
    if (cc + 3 < NCC) LOAD_REGS(B, cc + 3);
    compute(cc + 1);
    __syncthreads();
  }

#undef LOAD_REGS
#undef WMUL
#undef STORE_LDS

  // write partials: part[(tg*2 + comp)*131072 + b*512 + p]
  float* psb = part + ((size_t)tg * 2 + 0) * 131072;
  float* pnb = part + ((size_t)tg * 2 + 1) * 131072;
#pragma unroll
  for (int i = 0; i < 16; ++i) {
    const int drow = (i & 3) + 8 * (i >> 2) + 4 * hi;
    const size_t o = (size_t)(b0 + wm * 32 + drow) * 512 + p0 + wn * 32 + fr;
    psb[o] = sac[i];
    pnb[o] = nac[i];
  }
}

// ===========================================================================
// MERGE: plain sums of the NG t-group partials, bias, relu.
// ===========================================================================
template <int NG>
__global__ __launch_bounds__(256) void merge_kernel(
    const float* __restrict__ part, const float* __restrict__ fcb,
    float* __restrict__ out) {
  const int pair = blockIdx.x * 256 + threadIdx.x;
  float S = 0.f, N = 0.f;
#pragma unroll
  for (int k = 0; k < NG; ++k) {
    S += part[((size_t)k * 2 + 0) * 131072 + pair];
    N += part[((size_t)k * 2 + 1) * 131072 + pair];
  }
  float o = N * __builtin_amdgcn_rcpf(S) + fcb[0];
  out[pair] = fmaxf(o, 0.f);
}

// ===========================================================================
// FALLBACK (round-2 kernel, used only if ws_size is too small)
// ===========================================================================
__global__ __launch_bounds__(1024) void proto_mfma_kernel(
    const float* __restrict__ x, const float* __restrict__ proto,
    const float* __restrict__ fcw, const float* __restrict__ fcb,
    float* __restrict__ out) {
  __shared__ unsigned xs[56 * 289];
  __shared__ unsigned ps[56 * 145];
  __shared__ unsigned pws[56 * 145];

  const int tid = threadIdx.x;
  const int l = tid & 63;
  const int w = tid >> 6;
  const int bq = w & 1;
  const int tq = w >> 1;
  const int t0 = tq * 7;

  const int n = blockIdx.y * 32 + blockIdx.x;
  const int p0 = (n >> 3) * 16;
  const int b0 = (n & 7) * 32;

  const bool act = (l < 56);
  const int lt = l;

  const int xbase0 = ((b0 + 2 * w + 0) * kC) * kT + lt;
  const int xbase1 = ((b0 + 2 * w + 1) * kC) * kT + lt;
  const int pbase = ((p0 + w) * kC) * kT + lt;

  const int arow = l & 15;
  const int q2 = (l >> 4) << 1;
  const int xoff = (bq * 16 + arow) * 9 + q2;
  const int poff = arow * 9 + q2;

  v4f acc[7][2];
#pragma unroll
  for (int ti = 0; ti < 7; ++ti) {
    acc[ti][0] = v4f{0.f, 0.f, 0.f, 0.f};
    acc[ti][1] = v4f{0.f, 0.f, 0.f, 0.f};
  }
  float xn2a = 0.f, xn2b = 0.f, pn2 = 0.f;

#pragma unroll 1
  for (int st = 0; st < 32; ++st) {
    const int k0 = st * 16;
    if (act) {
#pragma unroll
      for (int r = 0; r < 16; ++r) {
        const int cw = r & 7;
        const int c = k0 + 2 * cw;
        const int ga = ((r >> 3) ? xbase1 : xbase0) + c * kT;
        float g0 = x[ga], g1 = x[ga + kT];
        if (r >> 3) xn2b = fmaf(g0, g0, fmaf(g1, g1, xn2b));
        else xn2a = fmaf(g0, g0, fmaf(g1, g1, xn2a));
        xs[lt * 289 + (2 * w + (r >> 3)) * 9 + cw] = pack_bf16(g0, g1);
      }
#pragma unroll
      for (int cw = 0; cw < 8; ++cw) {
        const int c = k0 + 2 * cw;
        const int ga = pbase + c * kT;
        float g0 = proto[ga], g1 = proto[ga + kT];
        pn2 = fmaf(g0, g0, fmaf(g1, g1, pn2));
        ps[lt * 145 + w * 9 + cw] = pack_bf16(g0, g1);
        float f0 = fcw[c], f1 = fcw[c + 1];
        pws[lt * 145 + w * 9 + cw] = pack_bf16(g0 * f0, g1 * f1);
      }
    }
    __syncthreads();
#pragma unroll
    for (int ti = 0; ti < 7; ++ti) {
      const int t = t0 + ti;
      unsigned xw0 = xs[t * 289 + xoff];
      unsigned xw1 = xs[t * 289 + xoff + 1];
      unsigned pw0 = ps[t * 145 + poff];
      unsigned pw1 = ps[t * 145 + poff + 1];
      unsigned ww0 = pws[t * 145 + poff];
      unsigned ww1 = pws[t * 145 + poff + 1];
      v4s af = frag2(xw0, xw1);
      v4s bf = frag2(pw0, pw1);
      v4s wf = frag2(ww0, ww1);
      acc[ti][0] = __builtin_amdgcn_mfma_f32_16x16x16bf16_1k(af, bf, acc[ti][0], 0, 0, 0);
      acc[ti][1] = __builtin_amdgcn_mfma_f32_16x16x16bf16_1k(af, wf, acc[ti][1], 0, 0, 0);
    }
    __syncthreads();
  }

  float* xnorm = (float*)ps;
  float* pnorm = xnorm + 32 * 56;
  if (act) {
    xnorm[(2 * w + 0) * 56 + lt] = xn2a;
    xnorm[(2 * w + 1) * 56 + lt] = xn2b;
    pnorm[w * 56 + lt] = pn2;
  }
  __syncthreads();

  float* fm = (float*)xs;
  float* fsum = fm + 4096;
  float* fnum = fsum + 4096;
  const int pc = arow;
  const int qq = l >> 4;
#pragma unroll
  for (int i = 0; i < 4; ++i) {
    const int bl = bq * 16 + 4 * qq + i;
    float m = -3.0e38f;
    float sims[7];
#pragma unroll
    for (int ti = 0; ti < 7; ++ti) {
      const int t = t0 + ti;
      float den = fmaxf(sqrtf(xnorm[bl * 56 + t]) * sqrtf(pnorm[pc * 56 + t]), 1e-8f);
      float s = acc[ti][0][i] / den;
      sims[ti] = s;
      m = fmaxf(m, s);
    }
    float se = 0.f, nu = 0.f;
#pragma unroll
    for (int ti = 0; ti < 7; ++ti) {
      float e = __expf(sims[ti] - m);
      se += e;
      nu = fmaf(e, acc[ti][1][i], nu);
    }
    const int pair = bl * 16 + pc;
    fm[tq * 512 + pair] = m;
    fsum[tq * 512 + pair] = se;
    fnum[tq * 512 + pair] = nu;
  }
  __syncthreads();

  if (tid < 512) {
    float M = -3.0e38f;
#pragma unroll
    for (int k = 0; k < 8; ++k) M = fmaxf(M, fm[k * 512 + tid]);
    float S = 0.f, N = 0.f;
#pragma unroll
    for (int k = 0; k < 8; ++k) {
      float sc = __expf(fm[k * 512 + tid] - M);
      S = fmaf(fsum[k * 512 + tid], sc, S);
      N = fmaf(fnum[k * 512 + tid], sc, N);
    }
    float o = N / S + fcb[0];
    out[(b0 + (tid >> 4)) * kP + p0 + (tid & 15)] = fmaxf(o, 0.f);
  }
}

// ===========================================================================
extern "C" void kernel_launch(void* const* d_in, const int* in_sizes, int n_in,
                              void* d_out, int out_size, void* d_ws, size_t ws_size,
                              hipStream_t stream) {
  const float* x = (const float*)d_in[0];
  const float* proto = (const float*)d_in[1];
  const float* fcw = (const float*)d_in[2];
  const float* fcb = (const float*)d_in[3];
  float* out = (float*)d_out;

  // ws layouts (words): xt 3,670,016 | pt 7,340,032 | part z*2*131072 |
  // xn 14,336 | pn 28,672
  //   TPB=2 (z=28): total 18,393,088 w = 73,572,352 B
  //   TPB=4 (z=14): total 14,723,072 w = 58,892,288 B
  const size_t need2 = 73572352;
  const size_t need4 = 58892288;
  if (ws_size >= need4) {
    const bool big = (ws_size >= need2);
    unsigned* xt = (unsigned*)d_ws;
    unsigned* ptb = xt + 3670016;
    float* partb = (float*)(xt + 11010048);
    const size_t partw = big ? (size_t)28 * 2 * 131072 : (size_t)14 * 2 * 131072;
    float* xnb = (float*)(xt + 11010048) + partw;
    float* pnb = xnb + 14336;

    hipLaunchKernelGGL(prep_kernel, dim3(kB + kP), dim3(512), 0, stream,
                       x, proto, xt, ptb, xnb, pnb);
    if (big) {
      hipLaunchKernelGGL(proto_gemm_kernel<2>, dim3(4, 8, 28), dim3(256), 0, stream,
                         xt, ptb, fcw, xnb, pnb, partb);
      hipLaunchKernelGGL(merge_kernel<28>, dim3(512), dim3(256), 0, stream,
                         partb, fcb, out);
    } else {
      hipLaunchKernelGGL(proto_gemm_kernel<4>, dim3(4, 8, 14), dim3(256), 0, stream,
                         xt, ptb, fcw, xnb, pnb, partb);
      hipLaunchKernelGGL(merge_kernel<14>, dim3(512), dim3(256), 0, stream,
                         partb, fcb, out);
    }
  } else {
    hipLaunchKernelGGL(proto_mfma_kernel, dim3(32, 8), dim3(1024), 0, stream,
                       x, proto, fcw, fcb, out);
  }
}